// Round 1
// baseline (141.727 us; speedup 1.0000x reference)
//
#include <hip/hip_runtime.h>
#include <math.h>

#define EPSF 1e-8f

constexpr int B = 262144;
constexpr int T = 128;
constexpr int E = 5;
constexpr int K = 20;

// ws[0] = sum((pred-targ)^2 * mask), ws[1] = sum(mask), ws[2] = sum(ll)
__global__ void k_init(float* ws) {
    if (threadIdx.x < 4) ws[threadIdx.x] = 0.0f;
}

__global__ __launch_bounds__(256) void k_state(const float4* __restrict__ pred,
                                               const float4* __restrict__ targ,
                                               const float4* __restrict__ mask,
                                               float* __restrict__ ws, int n4) {
    int tid = blockIdx.x * blockDim.x + threadIdx.x;
    int stride = gridDim.x * blockDim.x;
    float s = 0.f, m = 0.f;
    for (int i = tid; i < n4; i += stride) {
        float4 p = pred[i];
        float4 t = targ[i];
        float4 w = mask[i];
        float d0 = p.x - t.x, d1 = p.y - t.y, d2 = p.z - t.z, d3 = p.w - t.w;
        s += d0 * d0 * w.x + d1 * d1 * w.y + d2 * d2 * w.z + d3 * d3 * w.w;
        m += w.x + w.y + w.z + w.w;
    }
    #pragma unroll
    for (int off = 32; off > 0; off >>= 1) {
        s += __shfl_down(s, off);
        m += __shfl_down(m, off);
    }
    __shared__ float ss[4], sm[4];
    int wid = threadIdx.x >> 6;
    if ((threadIdx.x & 63) == 0) { ss[wid] = s; sm[wid] = m; }
    __syncthreads();
    if (threadIdx.x == 0) {
        atomicAdd(&ws[0], ss[0] + ss[1] + ss[2] + ss[3]);
        atomicAdd(&ws[1], sm[0] + sm[1] + sm[2] + sm[3]);
    }
}

__global__ __launch_bounds__(256) void k_surv(const float* __restrict__ hz,
                                              const float* __restrict__ et,
                                              const float* __restrict__ ei,
                                              float* __restrict__ ws) {
    int b = blockIdx.x * 256 + threadIdx.x;
    float ll = 0.f;
    #pragma unroll
    for (int e = 0; e < E; ++e) {
        float t = et[b * E + e];
        float ind = ei[b * E + e];
        // searchsorted(bounds={0.5,1.0,...,10.0}, t, side='left') == count of bounds < t
        // bounds are exact multiples of 0.5, so compare m*0.5 < t  <=>  m < 2t (exact).
        float u = 2.0f * t;
        int idx = (int)floorf(u);
        if ((float)idx == u) idx -= 1;
        idx = min(max(idx, 0), K - 1);
        const float4* row = (const float4*)(hz + ((size_t)e * B + b) * K);
        float cum = 0.f, ls = 0.f, lp = 0.f;
        #pragma unroll
        for (int q = 0; q < K / 4; ++q) {
            float4 v = row[q];
            float x0 = v.x, x1 = v.y, x2 = v.z, x3 = v.w;
            float xs[4] = {x0, x1, x2, x3};
            #pragma unroll
            for (int j = 0; j < 4; ++j) {
                int k = q * 4 + j;
                float p = 1.0f / (1.0f + __expf(-xs[j]));
                if (k == idx) { ls = cum; lp = __logf(p + EPSF); }
                cum += __logf(1.0f - p + EPSF);   // after the check: exclusive prefix
            }
        }
        ll += ls + (ind > 0.5f ? lp : 0.0f);
    }
    #pragma unroll
    for (int off = 32; off > 0; off >>= 1) ll += __shfl_down(ll, off);
    __shared__ float sl[4];
    int wid = threadIdx.x >> 6;
    if ((threadIdx.x & 63) == 0) sl[wid] = ll;
    __syncthreads();
    if (threadIdx.x == 0) atomicAdd(&ws[2], sl[0] + sl[1] + sl[2] + sl[3]);
}

__global__ void k_fin(const float* __restrict__ ws, float* __restrict__ out) {
    if (threadIdx.x == 0 && blockIdx.x == 0) {
        float state_loss = ws[0] / (ws[1] + EPSF);
        float surv_loss = -ws[2] / (float)(E * B);
        out[0] = state_loss + surv_loss;
    }
}

extern "C" void kernel_launch(void* const* d_in, const int* in_sizes, int n_in,
                              void* d_out, int out_size, void* d_ws, size_t ws_size,
                              hipStream_t stream) {
    const float* pred = (const float*)d_in[0];
    const float* hz   = (const float*)d_in[1];
    const float* targ = (const float*)d_in[2];
    const float* mask = (const float*)d_in[3];
    const float* et   = (const float*)d_in[4];
    const float* ei   = (const float*)d_in[5];
    float* out = (float*)d_out;
    float* ws  = (float*)d_ws;

    hipLaunchKernelGGL(k_init, dim3(1), dim3(64), 0, stream, ws);

    int n4 = (B * T) / 4;  // 8,388,608 float4s
    hipLaunchKernelGGL(k_state, dim3(2048), dim3(256), 0, stream,
                       (const float4*)pred, (const float4*)targ,
                       (const float4*)mask, ws, n4);

    hipLaunchKernelGGL(k_surv, dim3(B / 256), dim3(256), 0, stream, hz, et, ei, ws);

    hipLaunchKernelGGL(k_fin, dim3(1), dim3(1), 0, stream, ws, out);
}